// Round 9
// baseline (1314.539 us; speedup 1.0000x reference)
//
#include <hip/hip_runtime.h>

typedef _Float16 f16;
typedef _Float16 half8 __attribute__((ext_vector_type(8)));
typedef _Float16 half4v __attribute__((ext_vector_type(4)));
typedef float f32x4 __attribute__((ext_vector_type(4)));

#define N_ATOMS 100000
#define N_EDGES 200000
#define N_MOLS  4096
#define D_V 133
#define D_E 14
#define D_H 512
#define KC  672        // padded K for [W_h(512); W_i(147)] and [W_o_m(512); W_o_v(133)]
#define KSE 21         // 32-wide K tiles
#define LDA 40         // LDS A-tile row stride (f16 elems): 80 B rows

// ---- weight build, swizzled to MFMA fragment order:
//   B_swz[(((n>>4)*21 + (k>>5))*64 + ((k>>3)&3)*16 + (n&15))*8 + (k&7)] = W[k][n]
__global__ void wt_build_swz(const float* __restrict__ W1, int r1,
                             const float* __restrict__ W2, int r2,
                             f16* __restrict__ WtS) {
    int gid = blockIdx.x * blockDim.x + threadIdx.x;
    if (gid >= D_H * KC) return;
    int n = gid / KC;
    int k = gid - n * KC;
    float x = 0.f;
    if (k < r1) x = W1[k * D_H + n];
    else if (k < r1 + r2) x = W2[(k - r1) * D_H + n];
    const int dst = ((((n >> 4) * KSE + (k >> 5)) << 6) + (((k >> 3) & 3) << 4) + (n & 15)) * 8 + (k & 7);
    WtS[dst] = (f16)x;
}

// ---- CSR build over edge_dst
__global__ void csr_hist(const int* __restrict__ edst, int* __restrict__ cnt) {
    int e = blockIdx.x * blockDim.x + threadIdx.x;
    if (e < N_EDGES) atomicAdd(&cnt[edst[e]], 1);
}

__global__ __launch_bounds__(1024) void csr_scan(const int* __restrict__ cnt,
                                                 int* __restrict__ off, int* __restrict__ pos) {
    __shared__ int sums[1024];
    const int tid = threadIdx.x;
    const int lo = tid * 100;            // 1000 active threads x 100 atoms, int4-aligned
    int s = 0;
    if (lo < N_ATOMS) {
        const int4* c4 = reinterpret_cast<const int4*>(cnt + lo);
        #pragma unroll
        for (int i = 0; i < 25; ++i) { int4 v = c4[i]; s += v.x + v.y + v.z + v.w; }
    }
    sums[tid] = s;
    __syncthreads();
    for (int d = 1; d < 1024; d <<= 1) {
        int v = (tid >= d) ? sums[tid - d] : 0;
        __syncthreads();
        sums[tid] += v;
        __syncthreads();
    }
    int run = sums[tid] - s;  // exclusive base
    if (lo < N_ATOMS) {
        const int4* c4 = reinterpret_cast<const int4*>(cnt + lo);
        for (int i = 0; i < 25; ++i) {
            int4 v = c4[i];          // load before aliased pos-store (pos == cnt)
            const int b = lo + i * 4;
            off[b]     = run; pos[b]     = run; run += v.x;
            off[b + 1] = run; pos[b + 1] = run; run += v.y;
            off[b + 2] = run; pos[b + 2] = run; run += v.z;
            off[b + 3] = run; pos[b + 3] = run; run += v.w;
        }
    }
    if (tid == 1023) off[N_ATOMS] = run;   // s==0 here -> run == total
}

__global__ void csr_scatter(const int* __restrict__ edst, int* __restrict__ pos,
                            int* __restrict__ eid) {
    int e = blockIdx.x * blockDim.x + threadIdx.x;
    if (e < N_EDGES) {
        int idx = atomicAdd(&pos[edst[e]], 1);
        eid[idx] = e;
    }
}

// ---- node message sum via CSR gather.  F16M: store f16 rows.  else: block-scaled int8.
template<bool F16M>
__global__ __launch_bounds__(512) void seg_csr(
    const f16* __restrict__ H, const int* __restrict__ off, const int* __restrict__ eid,
    void* __restrict__ MnOut, float* __restrict__ Msc)
{
    const int n = blockIdx.x * 8 + (threadIdx.x >> 6);
    const int lane = threadIdx.x & 63;
    const int j0 = off[n], j1 = off[n + 1];
    float acc[8];
    #pragma unroll
    for (int k = 0; k < 8; ++k) acc[k] = 0.f;
    int e_cur = (j0 < j1) ? eid[j0] : 0;
    for (int j = j0; j < j1; ++j) {
        const int e_nxt = (j + 1 < j1) ? eid[j + 1] : 0;   // prefetch next index
        const half8 h = *reinterpret_cast<const half8*>(&H[e_cur * D_H + lane * 8]);
        #pragma unroll
        for (int k = 0; k < 8; ++k) acc[k] += (float)h[k];
        e_cur = e_nxt;
    }
    if (F16M) {
        half8 o;
        #pragma unroll
        for (int k = 0; k < 8; ++k) o[k] = (f16)acc[k];
        *reinterpret_cast<half8*>(&((f16*)MnOut)[n * D_H + lane * 8]) = o;
    } else {
        float m = 0.f;
        #pragma unroll
        for (int k = 0; k < 8; ++k) m = fmaxf(m, fabsf(acc[k]));
        m = fmaxf(m, __shfl_xor(m, 1));
        m = fmaxf(m, __shfl_xor(m, 2));
        m = fmaxf(m, 1e-20f);
        const float s = m * (1.f / 127.f);
        const float inv_s = 127.f / m;
        if ((lane & 3) == 0) Msc[n * 16 + (lane >> 2)] = s;
        int q[8];
        #pragma unroll
        for (int k = 0; k < 8; ++k) q[k] = __float2int_rn(acc[k] * inv_s);
        uint2 o;
        o.x = (q[0] & 0xff) | ((q[1] & 0xff) << 8) | ((q[2] & 0xff) << 16) | ((unsigned)(q[3] & 0xff) << 24);
        o.y = (q[4] & 0xff) | ((q[5] & 0xff) << 8) | ((q[6] & 0xff) << 16) | ((unsigned)(q[7] & 0xff) << 24);
        *reinterpret_cast<uint2*>(&((unsigned int*)MnOut)[n * 128 + lane * 2]) = o;
    }
}

// ---- R9: streaming message materialization, IN PLACE over Ha.
//      Msg[e] = Mn[esrc[e]] (dequant) - Ha[e^1].  rev = e^1 -> pairs are adjacent:
//      one wave owns pair (2i, 2i+1): reads both 1KB rows + two gathered Mn rows,
//      writes both rows back.  Zero extra workspace, no cross-pair deps.
//      This moves the random Mn gather OUT of the barrier-structured GEMM (where it
//      convoy-serialized at 8B/lane per K-step, R0-R8 plateau ~297us) into a pure
//      streaming kernel with full TLP; Mn (51.2MB int8 / 102.4MB f16) is L2/L3-hot.
template<bool F16M>
__global__ __launch_bounds__(256) void msg_build(
    const int* __restrict__ esrc, const void* __restrict__ Mn,
    const float* __restrict__ Msc, f16* __restrict__ Ha)
{
    const int p = blockIdx.x * 4 + (threadIdx.x >> 6);   // pair index, 4 pairs/block
    const int lane = threadIdx.x & 63;
    const int e0 = 2 * p, e1 = 2 * p + 1;
    const int sv0 = esrc[e0], sv1 = esrc[e1];
    const half8 h0 = *reinterpret_cast<const half8*>(&Ha[e0 * D_H + lane * 8]);
    const half8 h1 = *reinterpret_cast<const half8*>(&Ha[e1 * D_H + lane * 8]);
    half8 w0, w1;
    if (F16M) {
        const half8 m0 = *reinterpret_cast<const half8*>(&((const f16*)Mn)[sv0 * D_H + lane * 8]);
        const half8 m1 = *reinterpret_cast<const half8*>(&((const f16*)Mn)[sv1 * D_H + lane * 8]);
        w0 = m0 - h1;
        w1 = m1 - h0;
    } else {
        const uint2 q0 = *reinterpret_cast<const uint2*>(&((const unsigned int*)Mn)[sv0 * 128 + lane * 2]);
        const uint2 q1 = *reinterpret_cast<const uint2*>(&((const unsigned int*)Mn)[sv1 * 128 + lane * 2]);
        const float s0 = Msc[sv0 * 16 + (lane >> 2)];
        const float s1 = Msc[sv1 * 16 + (lane >> 2)];
        #pragma unroll
        for (int k = 0; k < 8; ++k) {
            const int b0 = (int)(char)(((k < 4) ? q0.x : q0.y) >> ((k & 3) * 8));
            const int b1 = (int)(char)(((k < 4) ? q1.x : q1.y) >> ((k & 3) * 8));
            w0[k] = (f16)((float)b0 * s0 - (float)h1[k]);
            w1[k] = (f16)((float)b1 * s1 - (float)h0[k]);
        }
    }
    *reinterpret_cast<half8*>(&Ha[e0 * D_H + lane * 8]) = w0;
    *reinterpret_cast<half8*>(&Ha[e1 * D_H + lane * 8]) = w1;
}

// ---- R9: edge GEMM with SEQUENTIAL A (Msg lives in Ha): Ha[e] = relu([Msg(512);
//      V[sv](133); E[e](14)] @ [W_h; W_i]).  Since A-rows are now sequential, use
//      the R2/gemm_out structure (proven fastest for sequential sources): LDS
//      double-buffer (1 barrier/iter) + 2-deep NAMED slots, rolled unroll-2, peeled
//      last iter.  No ph operand, no dequant -> fewer live regs than gemm_out.
//      KS0=16 instance is the init pass (H = relu(H0), reads no Msg).
//      In-place epilogue safe: each block reads only its own 64 rows; all A-loads
//      are consumed into LDS (barrier-ordered) before the epilogue stores.
template<int KS0>
__global__ __launch_bounds__(512) void gemm_edge(
    const float* __restrict__ V, const float* __restrict__ E,
    const int* __restrict__ esrc,
    f16* __restrict__ Ha, const f16* __restrict__ WtS)
{
    __shared__ __align__(16) f16 Al[2][64 * LDA];
    const int tid = threadIdx.x;
    const int rowblk = blockIdx.x << 6;
    const int srow = tid >> 3;
    const int skk  = (tid & 7) << 2;
    const int e_s  = rowblk + srow;
    const int sv   = esrc[e_s];
    const int lane = tid & 63;
    const int quad = lane >> 4;
    const int m16  = lane & 15;
    const int colbase = (tid >> 6) << 6;
    const int cb0 = (tid >> 6) << 2;
    const f16* WtL = WtS + lane * 8;

    f32x4 acc[4][4];
    #pragma unroll
    for (int a = 0; a < 4; ++a)
    #pragma unroll
    for (int b = 0; b < 4; ++b)
    #pragma unroll
    for (int r = 0; r < 4; ++r) acc[a][b][r] = 0.f;

    half4v pm0, pm1;
    float pv0[4], pv1[4];

#define GE_ISSUE(S, KSV) do {                                                        \
    const int ks_i_ = (KSV);                                                         \
    if (ks_i_ < KSE) {                                                               \
        const int k0_ = ks_i_ << 5;                                                  \
        if (k0_ < D_H) {                                                             \
            pm##S = *reinterpret_cast<const half4v*>(&Ha[e_s * D_H + k0_ + skk]);    \
        } else {                                                                     \
            const int kb_ = k0_ + skk - D_H;                                         \
            pv##S[0] = (kb_ + 0 < D_V) ? V[sv * D_V + kb_ + 0] : ((kb_ + 0 < D_V + D_E) ? E[e_s * D_E + kb_ + 0 - D_V] : 0.f); \
            pv##S[1] = (kb_ + 1 < D_V) ? V[sv * D_V + kb_ + 1] : ((kb_ + 1 < D_V + D_E) ? E[e_s * D_E + kb_ + 1 - D_V] : 0.f); \
            pv##S[2] = (kb_ + 2 < D_V) ? V[sv * D_V + kb_ + 2] : ((kb_ + 2 < D_V + D_E) ? E[e_s * D_E + kb_ + 2 - D_V] : 0.f); \
            pv##S[3] = (kb_ + 3 < D_V) ? V[sv * D_V + kb_ + 3] : ((kb_ + 3 < D_V + D_E) ? E[e_s * D_E + kb_ + 3 - D_V] : 0.f); \
        }                                                                            \
    }                                                                                \
} while (0)

#define GE_MAKEW(S, KSV, W) do {                                                     \
    const int k0_ = (KSV) << 5;                                                      \
    if (k0_ < D_H) { W = pm##S; }                                                    \
    else {                                                                           \
        W[0] = (f16)pv##S[0]; W[1] = (f16)pv##S[1];                                  \
        W[2] = (f16)pv##S[2]; W[3] = (f16)pv##S[3];                                  \
    }                                                                                \
} while (0)

#define GE_MFMA(KSV, CUR) do {                                                       \
    half8 af[4];                                                                     \
    _Pragma("unroll")                                                                \
    for (int rt = 0; rt < 4; ++rt)                                                   \
        af[rt] = *reinterpret_cast<const half8*>(&Al[CUR][(rt * 16 + m16) * LDA + quad * 8]); \
    _Pragma("unroll")                                                                \
    for (int ct = 0; ct < 4; ++ct) {                                                 \
        const half8 bf = *reinterpret_cast<const half8*>(&WtL[(((cb0 + ct) * KSE + (KSV)) << 9)]); \
        _Pragma("unroll")                                                            \
        for (int rt = 0; rt < 4; ++rt)                                               \
            acc[rt][ct] = __builtin_amdgcn_mfma_f32_16x16x32_f16(af[rt], bf, acc[rt][ct], 0, 0, 0); \
    }                                                                                \
} while (0)

    GE_ISSUE(0, KS0);
    GE_ISSUE(1, KS0 + 1);
    {
        half4v w;
        GE_MAKEW(0, KS0, w);
        *reinterpret_cast<half4v*>(&Al[0][srow * LDA + skk]) = w;
        GE_ISSUE(0, KS0 + 2);
    }
    __syncthreads();

    constexpr int NT = KSE - KS0;   // 21 or 5; NT-1 even -> unroll-2 friendly
    #pragma unroll 2
    for (int i = 0; i < NT - 1; ++i) {
        const int ks = KS0 + i;
        const int cur = i & 1;
        {
            half4v w;
            if ((i + 1) & 1) { GE_MAKEW(1, ks + 1, w); }
            else             { GE_MAKEW(0, ks + 1, w); }
            *reinterpret_cast<half4v*>(&Al[cur ^ 1][srow * LDA + skk]) = w;
            if ((i + 1) & 1) { GE_ISSUE(1, ks + 3); }
            else             { GE_ISSUE(0, ks + 3); }
        }
        GE_MFMA(ks, cur);
        __syncthreads();
    }
    GE_MFMA(KSE - 1, (NT - 1) & 1);

#undef GE_ISSUE
#undef GE_MAKEW
#undef GE_MFMA

    #pragma unroll
    for (int rt = 0; rt < 4; ++rt)
    #pragma unroll
    for (int ct = 0; ct < 4; ++ct)
    #pragma unroll
    for (int r = 0; r < 4; ++r) {
        const int row = rowblk + rt * 16 + quad * 4 + r;
        const int col = colbase + ct * 16 + m16;
        Ha[row * D_H + col] = (f16)fmaxf(acc[rt][ct][r], 0.f);
    }
}

// ---- output GEMM: Hv[a] = relu([M_v(512); V(133)] @ WtO + b_o).
//      R2-STRUCTURE (proven fastest variant): LDS double-buffer (1 barrier/iter) +
//      2-deep NAMED prefetch slots, rolled #pragma unroll 2 (trip 20, even), peeled
//      last iter.  Mn[arow] here is SEQUENTIAL (no gather).
template<bool F16M>
__global__ __launch_bounds__(512) void gemm_out(
    const float* __restrict__ V, const void* __restrict__ Mn,
    const float* __restrict__ Msc, const float* __restrict__ bo,
    const f16* __restrict__ WtS, f16* __restrict__ Hv)
{
    __shared__ __align__(16) f16 Al[2][64 * LDA];
    __shared__ float bo_s[D_H];
    const int tid = threadIdx.x;
    const int rowblk = blockIdx.x << 6;
    bo_s[tid] = bo[tid];
    const int srow = tid >> 3;
    const int skk  = (tid & 7) << 2;
    const int arow = min(rowblk + srow, N_ATOMS - 1);
    const int lane = tid & 63;
    const int quad = lane >> 4;
    const int m16  = lane & 15;
    const int colbase = (tid >> 6) << 6;
    const int cb0 = (tid >> 6) << 2;
    const f16* WtL = WtS + lane * 8;

    f32x4 acc[4][4];
    #pragma unroll
    for (int a = 0; a < 4; ++a)
    #pragma unroll
    for (int b = 0; b < 4; ++b)
    #pragma unroll
    for (int r = 0; r < 4; ++r) acc[a][b][r] = 0.f;

    char4 pq0, pq1; float ps0, ps1;
    half4v pm0, pm1;
    float pv0[4], pv1[4];

#define GO_ISSUE(S, KSV) do {                                                        \
    const int ks_i_ = (KSV);                                                         \
    if (ks_i_ < KSE) {                                                               \
        const int k0_ = ks_i_ << 5;                                                  \
        if (k0_ < D_H) {                                                             \
            if (F16M) {                                                              \
                pm##S = *reinterpret_cast<const half4v*>(&((const f16*)Mn)[arow * D_H + k0_ + skk]); \
            } else {                                                                 \
                pq##S = *reinterpret_cast<const char4*>(&((const char*)Mn)[arow * D_H + k0_ + skk]); \
                ps##S = Msc[arow * 16 + (k0_ >> 5)];                                 \
            }                                                                        \
        } else {                                                                     \
            const int kb_ = k0_ + skk - D_H;                                         \
            pv##S[0] = (kb_ + 0 < D_V) ? V[arow * D_V + kb_ + 0] : 0.f;              \
            pv##S[1] = (kb_ + 1 < D_V) ? V[arow * D_V + kb_ + 1] : 0.f;              \
            pv##S[2] = (kb_ + 2 < D_V) ? V[arow * D_V + kb_ + 2] : 0.f;              \
            pv##S[3] = (kb_ + 3 < D_V) ? V[arow * D_V + kb_ + 3] : 0.f;              \
        }                                                                            \
    }                                                                                \
} while (0)

#define GO_MAKEW(S, KSV, W) do {                                                     \
    const int k0_ = (KSV) << 5;                                                      \
    if (k0_ < D_H) {                                                                 \
        if (F16M) { W = pm##S; }                                                     \
        else {                                                                       \
            W[0] = (f16)((float)pq##S.x * ps##S);                                    \
            W[1] = (f16)((float)pq##S.y * ps##S);                                    \
            W[2] = (f16)((float)pq##S.z * ps##S);                                    \
            W[3] = (f16)((float)pq##S.w * ps##S);                                    \
        }                                                                            \
    } else {                                                                         \
        W[0] = (f16)pv##S[0]; W[1] = (f16)pv##S[1];                                  \
        W[2] = (f16)pv##S[2]; W[3] = (f16)pv##S[3];                                  \
    }                                                                                \
} while (0)

#define GO_MFMA(KSV, CUR) do {                                                       \
    half8 af[4];                                                                     \
    _Pragma("unroll")                                                                \
    for (int rt = 0; rt < 4; ++rt)                                                   \
        af[rt] = *reinterpret_cast<const half8*>(&Al[CUR][(rt * 16 + m16) * LDA + quad * 8]); \
    _Pragma("unroll")                                                                \
    for (int ct = 0; ct < 4; ++ct) {                                                 \
        const half8 bf = *reinterpret_cast<const half8*>(&WtL[(((cb0 + ct) * KSE + (KSV)) << 9)]); \
        _Pragma("unroll")                                                            \
        for (int rt = 0; rt < 4; ++rt)                                               \
            acc[rt][ct] = __builtin_amdgcn_mfma_f32_16x16x32_f16(af[rt], bf, acc[rt][ct], 0, 0, 0); \
    }                                                                                \
} while (0)

    GO_ISSUE(0, 0);
    GO_ISSUE(1, 1);
    {
        half4v w;
        GO_MAKEW(0, 0, w);
        *reinterpret_cast<half4v*>(&Al[0][srow * LDA + skk]) = w;
        GO_ISSUE(0, 2);
    }
    __syncthreads();

    #pragma unroll 2
    for (int i = 0; i < KSE - 1; ++i) {
        const int ks = i;
        const int cur = i & 1;
        {
            half4v w;
            if ((i + 1) & 1) { GO_MAKEW(1, ks + 1, w); }
            else             { GO_MAKEW(0, ks + 1, w); }
            *reinterpret_cast<half4v*>(&Al[cur ^ 1][srow * LDA + skk]) = w;
            if ((i + 1) & 1) { GO_ISSUE(1, ks + 3); }
            else             { GO_ISSUE(0, ks + 3); }
        }
        GO_MFMA(ks, cur);
        __syncthreads();
    }
    GO_MFMA(KSE - 1, (KSE - 1) & 1);

#undef GO_ISSUE
#undef GO_MAKEW
#undef GO_MFMA

    #pragma unroll
    for (int rt = 0; rt < 4; ++rt)
    #pragma unroll
    for (int ct = 0; ct < 4; ++ct)
    #pragma unroll
    for (int r = 0; r < 4; ++r) {
        const int row = rowblk + rt * 16 + quad * 4 + r;
        if (row < N_ATOMS) {
            const int col = colbase + ct * 16 + m16;
            Hv[row * D_H + col] = (f16)fmaxf(acc[rt][ct][r] + bo_s[col], 0.f);
        }
    }
}

// ---- molecule mean: batch sorted -> contiguous atom range per mol (binary search)
__global__ __launch_bounds__(512) void mol_mean(
    const f16* __restrict__ Hv, const int* __restrict__ batch, float* __restrict__ mean)
{
    const int m = blockIdx.x;
    __shared__ int sh[2];
    if (threadIdx.x == 0) {
        int lo = 0, hi = N_ATOMS;
        while (lo < hi) { int mid = (lo + hi) >> 1; if (batch[mid] < m) lo = mid + 1; else hi = mid; }
        sh[0] = lo;
        int lo2 = lo; hi = N_ATOMS;
        while (lo2 < hi) { int mid = (lo2 + hi) >> 1; if (batch[mid] < m + 1) lo2 = mid + 1; else hi = mid; }
        sh[1] = lo2;
    }
    __syncthreads();
    const int a0 = sh[0], a1 = sh[1];
    float acc = 0.f;
    for (int a = a0; a < a1; ++a) acc += (float)Hv[(size_t)a * D_H + threadIdx.x];
    mean[m * D_H + threadIdx.x] = acc / (float)max(a1 - a0, 1);
}

__global__ __launch_bounds__(256) void bn_stats(
    const float* __restrict__ mean_in, const float* __restrict__ gamma,
    const float* __restrict__ beta, float* __restrict__ An, float* __restrict__ Bn)
{
    const int n = blockIdx.x;
    const int tid = threadIdx.x;
    float s = 0.f, s2 = 0.f;
    for (int m = tid; m < N_MOLS; m += 256) {
        float h = mean_in[m * D_H + n];
        s += h; s2 += h * h;
    }
    for (int off = 32; off > 0; off >>= 1) {
        s  += __shfl_down(s, off);
        s2 += __shfl_down(s2, off);
    }
    __shared__ float sh[8];
    const int wave = tid >> 6, lane = tid & 63;
    if (lane == 0) { sh[wave] = s; sh[4 + wave] = s2; }
    __syncthreads();
    if (tid == 0) {
        float S  = sh[0] + sh[1] + sh[2] + sh[3];
        float S2 = sh[4] + sh[5] + sh[6] + sh[7];
        float mu = S / (float)N_MOLS;
        float var = fmaxf(S2 / (float)N_MOLS - mu * mu, 0.f);
        float sc = rsqrtf(var + 1e-5f) * gamma[n];
        An[n] = sc;
        Bn[n] = beta[n] - mu * sc;
    }
}

__global__ void bn_apply(const float* __restrict__ mean_in,
                         const float* __restrict__ An, const float* __restrict__ Bn,
                         float* __restrict__ out)
{
    int gid = blockIdx.x * blockDim.x + threadIdx.x;
    int n = gid & 511;
    out[gid] = mean_in[gid] * An[n] + Bn[n];
}

extern "C" void kernel_launch(void* const* d_in, const int* in_sizes, int n_in,
                              void* d_out, int out_size, void* d_ws, size_t ws_size,
                              hipStream_t stream)
{
    (void)in_sizes; (void)n_in; (void)out_size;
    const float* V     = (const float*)d_in[0];
    const float* E     = (const float*)d_in[1];
    const int*   esrc  = (const int*)d_in[2];
    const int*   edst  = (const int*)d_in[3];
    const int*   batch = (const int*)d_in[4];
    const float* Wi    = (const float*)d_in[5];
    const float* Wh    = (const float*)d_in[6];
    const float* Wo    = (const float*)d_in[7];
    const float* bo    = (const float*)d_in[8];
    const float* gam   = (const float*)d_in[9];
    const float* bet   = (const float*)d_in[10];
    float* out = (float*)d_out;

    // workspace layout
    //  int8 mode total: 265,396,864 B.  f16 mode total: 310,196,864 B (needs ws_size >= that).
    char* ws = (char*)d_ws;
    f16*   WtC  = (f16*)(ws + 0);                   //    688,128 B (swizzled)
    f16*   WtO  = (f16*)(ws + 688128);              //    688,128 B (swizzled)
    int*   off  = (int*)(ws + 1376256);             //    400,128 B (N_ATOMS+1 ints)
    int*   eid  = (int*)(ws + 1776384);             //    800,000 B
    int*   cnt  = (int*)(ws + 2576384);             //    400,000 B (also 'pos' cursor)
    float* An   = (float*)(ws + 2992768);           //      2,048 B
    float* Bn   = (float*)(ws + 2994816);           //      2,048 B
    f16*   Ha   = (f16*)(ws + 2996864);             // 204,800,000 B (edge states; reused as Hv)
    void*  Mn   = (void*)(ws + 207796864);          // int8: 51.2 MB | f16: 102.4 MB
    float* Msc  = (float*)(ws + 258996864);         //   6,400,000 B scales (int8 mode only)
    f16*   Hv   = Ha;                                // Ha is dead after final seg_csr
    float* mean = out;                               // mol means live in d_out

    const bool f16m = ws_size >= 310196864ULL;

    // weights (swizzled to MFMA fragment order)
    wt_build_swz<<<(D_H * KC + 255) / 256, 256, 0, stream>>>(Wh, D_H, Wi, D_V + D_E, WtC);
    wt_build_swz<<<(D_H * KC + 255) / 256, 256, 0, stream>>>(Wo + D_V * D_H, D_H, Wo, D_V, WtO);

    // CSR over edge_dst (cnt doubles as scatter cursor 'pos')
    hipMemsetAsync(cnt, 0, 400000, stream);
    csr_hist<<<(N_EDGES + 511) / 512, 512, 0, stream>>>(edst, cnt);
    csr_scan<<<1, 1024, 0, stream>>>(cnt, off, cnt);
    csr_scatter<<<(N_EDGES + 511) / 512, 512, 0, stream>>>(edst, cnt, eid);

    // init pass: Ha = relu([V[src]; E] @ W_i)   (reads no Msg)
    gemm_edge<16><<<N_EDGES / 64, 512, 0, stream>>>(V, E, esrc, Ha, WtC);

    if (f16m) {
        for (int it = 0; it < 2; ++it) {
            seg_csr<true><<<N_ATOMS / 8, 512, 0, stream>>>(Ha, off, eid, Mn, Msc);
            msg_build<true><<<N_EDGES / 8, 256, 0, stream>>>(esrc, Mn, Msc, Ha);
            gemm_edge<0><<<N_EDGES / 64, 512, 0, stream>>>(V, E, esrc, Ha, WtC);
        }
        seg_csr<true><<<N_ATOMS / 8, 512, 0, stream>>>(Ha, off, eid, Mn, Msc);
        gemm_out<true><<<(N_ATOMS + 63) / 64, 512, 0, stream>>>(V, Mn, Msc, bo, WtO, Hv);
    } else {
        for (int it = 0; it < 2; ++it) {
            seg_csr<false><<<N_ATOMS / 8, 512, 0, stream>>>(Ha, off, eid, Mn, Msc);
            msg_build<false><<<N_EDGES / 8, 256, 0, stream>>>(esrc, Mn, Msc, Ha);
            gemm_edge<0><<<N_EDGES / 64, 512, 0, stream>>>(V, E, esrc, Ha, WtC);
        }
        seg_csr<false><<<N_ATOMS / 8, 512, 0, stream>>>(Ha, off, eid, Mn, Msc);
        gemm_out<false><<<(N_ATOMS + 63) / 64, 512, 0, stream>>>(V, Mn, Msc, bo, WtO, Hv);
    }

    mol_mean<<<N_MOLS, 512, 0, stream>>>(Hv, batch, mean);
    bn_stats<<<D_H, 256, 0, stream>>>(mean, gam, bet, An, Bn);
    bn_apply<<<(N_MOLS * D_H) / 256, 256, 0, stream>>>(mean, An, Bn, out);
}

// Round 10
// 1263.933 us; speedup vs baseline: 1.0400x; 1.0400x over previous
//
#include <hip/hip_runtime.h>

typedef _Float16 f16;
typedef _Float16 half8 __attribute__((ext_vector_type(8)));
typedef _Float16 half4v __attribute__((ext_vector_type(4)));
typedef float f32x4 __attribute__((ext_vector_type(4)));

#define N_ATOMS 100000
#define N_EDGES 200000
#define N_MOLS  4096
#define D_V 133
#define D_E 14
#define D_H 512
#define KC  672        // padded K for [W_h(512); W_i(147)] and [W_o_m(512); W_o_v(133)]
#define KSE 21         // 32-wide K tiles
#define LDA 40         // LDS A-tile row stride (f16 elems): 80 B rows

// ---- weight build, swizzled to MFMA fragment order:
//   B_swz[(((n>>4)*21 + (k>>5))*64 + ((k>>3)&3)*16 + (n&15))*8 + (k&7)] = W[k][n]
__global__ void wt_build_swz(const float* __restrict__ W1, int r1,
                             const float* __restrict__ W2, int r2,
                             f16* __restrict__ WtS) {
    int gid = blockIdx.x * blockDim.x + threadIdx.x;
    if (gid >= D_H * KC) return;
    int n = gid / KC;
    int k = gid - n * KC;
    float x = 0.f;
    if (k < r1) x = W1[k * D_H + n];
    else if (k < r1 + r2) x = W2[(k - r1) * D_H + n];
    const int dst = ((((n >> 4) * KSE + (k >> 5)) << 6) + (((k >> 3) & 3) << 4) + (n & 15)) * 8 + (k & 7);
    WtS[dst] = (f16)x;
}

// ---- CSR build over edge_dst
__global__ void csr_hist(const int* __restrict__ edst, int* __restrict__ cnt) {
    int e = blockIdx.x * blockDim.x + threadIdx.x;
    if (e < N_EDGES) atomicAdd(&cnt[edst[e]], 1);
}

__global__ __launch_bounds__(1024) void csr_scan(const int* __restrict__ cnt,
                                                 int* __restrict__ off, int* __restrict__ pos) {
    __shared__ int sums[1024];
    const int tid = threadIdx.x;
    const int lo = tid * 100;            // 1000 active threads x 100 atoms, int4-aligned
    int s = 0;
    if (lo < N_ATOMS) {
        const int4* c4 = reinterpret_cast<const int4*>(cnt + lo);
        #pragma unroll
        for (int i = 0; i < 25; ++i) { int4 v = c4[i]; s += v.x + v.y + v.z + v.w; }
    }
    sums[tid] = s;
    __syncthreads();
    for (int d = 1; d < 1024; d <<= 1) {
        int v = (tid >= d) ? sums[tid - d] : 0;
        __syncthreads();
        sums[tid] += v;
        __syncthreads();
    }
    int run = sums[tid] - s;  // exclusive base
    if (lo < N_ATOMS) {
        const int4* c4 = reinterpret_cast<const int4*>(cnt + lo);
        for (int i = 0; i < 25; ++i) {
            int4 v = c4[i];          // load before aliased pos-store (pos == cnt)
            const int b = lo + i * 4;
            off[b]     = run; pos[b]     = run; run += v.x;
            off[b + 1] = run; pos[b + 1] = run; run += v.y;
            off[b + 2] = run; pos[b + 2] = run; run += v.z;
            off[b + 3] = run; pos[b + 3] = run; run += v.w;
        }
    }
    if (tid == 1023) off[N_ATOMS] = run;   // s==0 here -> run == total
}

__global__ void csr_scatter(const int* __restrict__ edst, int* __restrict__ pos,
                            int* __restrict__ eid) {
    int e = blockIdx.x * blockDim.x + threadIdx.x;
    if (e < N_EDGES) {
        int idx = atomicAdd(&pos[edst[e]], 1);
        eid[idx] = e;
    }
}

// ---- node message sum via CSR gather.  F16M: store f16 rows.  else: block-scaled int8.
template<bool F16M>
__global__ __launch_bounds__(512) void seg_csr(
    const f16* __restrict__ H, const int* __restrict__ off, const int* __restrict__ eid,
    void* __restrict__ MnOut, float* __restrict__ Msc)
{
    const int n = blockIdx.x * 8 + (threadIdx.x >> 6);
    const int lane = threadIdx.x & 63;
    const int j0 = off[n], j1 = off[n + 1];
    float acc[8];
    #pragma unroll
    for (int k = 0; k < 8; ++k) acc[k] = 0.f;
    int e_cur = (j0 < j1) ? eid[j0] : 0;
    for (int j = j0; j < j1; ++j) {
        const int e_nxt = (j + 1 < j1) ? eid[j + 1] : 0;   // prefetch next index
        const half8 h = *reinterpret_cast<const half8*>(&H[e_cur * D_H + lane * 8]);
        #pragma unroll
        for (int k = 0; k < 8; ++k) acc[k] += (float)h[k];
        e_cur = e_nxt;
    }
    if (F16M) {
        half8 o;
        #pragma unroll
        for (int k = 0; k < 8; ++k) o[k] = (f16)acc[k];
        *reinterpret_cast<half8*>(&((f16*)MnOut)[n * D_H + lane * 8]) = o;
    } else {
        float m = 0.f;
        #pragma unroll
        for (int k = 0; k < 8; ++k) m = fmaxf(m, fabsf(acc[k]));
        m = fmaxf(m, __shfl_xor(m, 1));
        m = fmaxf(m, __shfl_xor(m, 2));
        m = fmaxf(m, 1e-20f);
        const float s = m * (1.f / 127.f);
        const float inv_s = 127.f / m;
        if ((lane & 3) == 0) Msc[n * 16 + (lane >> 2)] = s;
        int q[8];
        #pragma unroll
        for (int k = 0; k < 8; ++k) q[k] = __float2int_rn(acc[k] * inv_s);
        uint2 o;
        o.x = (q[0] & 0xff) | ((q[1] & 0xff) << 8) | ((q[2] & 0xff) << 16) | ((unsigned)(q[3] & 0xff) << 24);
        o.y = (q[4] & 0xff) | ((q[5] & 0xff) << 8) | ((q[6] & 0xff) << 16) | ((unsigned)(q[7] & 0xff) << 24);
        *reinterpret_cast<uint2*>(&((unsigned int*)MnOut)[n * 128 + lane * 2]) = o;
    }
}

// ---- fused message-passing GEMM (in-place on Ha), BK=32, 1-deep prefetch, swizzled B.
//      R10: the last unmeasured structure cell = {LDS dbuf + single __syncthreads/iter
//      + 1-deep prefetch}.  Measured neighbors: R0 sbuf/2-barrier/1-deep = 297us;
//      R2 dbuf/1-barrier/2-deep = 428 (VGPR 72 -> occupancy cliff, slots not dbuf);
//      R6 dbuf/raw-barrier+fences/1-deep = 342 (asm fences killed compiler overlap).
//      This keeps R0's exact register footprint (1-deep named slots, target 64 VGPR
//      -> 2 blocks/CU) and plain __syncthreads (no asm), halves barriers/K-step
//      (21 vs 42), staging write of tile k+1 overlaps MFMA of tile k.  Skeleton
//      validated at 64 VGPR by R9's gemm_edge on the sequential case.
//      Gather stays fused (R9 split: streaming msg_build cost > in-GEMM gather's
//      marginal ~40us).  If VGPR>64 or dur>=300: revert to R5, hold as final.
template<bool F16M, int KS0>
__global__ __launch_bounds__(512) void gemm_pass(
    const float* __restrict__ V, const float* __restrict__ E,
    const int* __restrict__ esrc, const void* __restrict__ Mn,
    const float* __restrict__ Msc,
    f16* __restrict__ Ha, const f16* __restrict__ WtS)
{
    __shared__ __align__(16) f16 Al[2][64 * LDA];
    const int tid = threadIdx.x;
    const int rowblk = blockIdx.x << 6;
    const int srow = tid >> 3;
    const int skk  = (tid & 7) << 2;
    const int e_s  = rowblk + srow;
    const int sv   = esrc[e_s];
    const int rev  = e_s ^ 1;
    const int lane = tid & 63;
    const int quad = lane >> 4;
    const int m16  = lane & 15;
    const int colbase = (tid >> 6) << 6;
    const int cb0 = (tid >> 6) << 2;          // first of this wave's 4 col-tiles
    const f16* WtL = WtS + lane * 8;          // lane-constant fragment base

    f32x4 acc[4][4];
    #pragma unroll
    for (int a = 0; a < 4; ++a)
    #pragma unroll
    for (int b = 0; b < 4; ++b)
    #pragma unroll
    for (int r = 0; r < 4; ++r) acc[a][b][r] = 0.f;

    // 1-deep prefetch registers (exactly R0's footprint)
    char4 pq; float ps; half4v pm; half4v ph; float pv[4];
    auto issue = [&](int ks) {
        const int k0 = ks << 5;
        if (k0 < D_H) {
            if (F16M) {
                pm = *reinterpret_cast<const half4v*>(&((const f16*)Mn)[sv * D_H + k0 + skk]);
            } else {
                pq = *reinterpret_cast<const char4*>(&((const char*)Mn)[sv * D_H + k0 + skk]);
                ps = Msc[sv * 16 + (k0 >> 5)];
            }
            ph = *reinterpret_cast<const half4v*>(&Ha[rev * D_H + k0 + skk]);
        } else {
            #pragma unroll
            for (int j = 0; j < 4; ++j) {
                const int kk = k0 + skk + j - D_H;
                float x = 0.f;
                if (kk < D_V) x = V[sv * D_V + kk];
                else if (kk < D_V + D_E) x = E[e_s * D_E + (kk - D_V)];
                pv[j] = x;
            }
        }
    };
    auto makew = [&](int ks) -> half4v {
        const int k0 = ks << 5;
        half4v w;
        if (k0 < D_H) {
            if (F16M) {
                w = pm - ph;   // packed f16 subtract
            } else {
                w[0] = (f16)((float)pq.x * ps - (float)ph[0]);
                w[1] = (f16)((float)pq.y * ps - (float)ph[1]);
                w[2] = (f16)((float)pq.z * ps - (float)ph[2]);
                w[3] = (f16)((float)pq.w * ps - (float)ph[3]);
            }
        } else {
            w[0] = (f16)pv[0]; w[1] = (f16)pv[1]; w[2] = (f16)pv[2]; w[3] = (f16)pv[3];
        }
        return w;
    };

#define GP_MFMA(KSV, CUR) do {                                                       \
    half8 af[4];                                                                     \
    _Pragma("unroll")                                                                \
    for (int rt = 0; rt < 4; ++rt)                                                   \
        af[rt] = *reinterpret_cast<const half8*>(&Al[CUR][(rt * 16 + m16) * LDA + quad * 8]); \
    _Pragma("unroll")                                                                \
    for (int ct = 0; ct < 4; ++ct) {                                                 \
        const half8 bf = *reinterpret_cast<const half8*>(&WtL[(((cb0 + ct) * KSE + (KSV)) << 9)]); \
        _Pragma("unroll")                                                            \
        for (int rt = 0; rt < 4; ++rt)                                               \
            acc[rt][ct] = __builtin_amdgcn_mfma_f32_16x16x32_f16(af[rt], bf, acc[rt][ct], 0, 0, 0); \
    }                                                                                \
} while (0)

    // prologue: gather(KS0) -> buf0; issue gather(KS0+1); publish
    issue(KS0);
    {
        half4v w = makew(KS0);            // compiler inserts the vmcnt wait
        *reinterpret_cast<half4v*>(&Al[0][srow * LDA + skk]) = w;
    }
    issue(KS0 + 1);
    __syncthreads();

    constexpr int NT = KSE - KS0;   // 21 or 5; NT-1 even -> unroll-2 keeps cur static
    #pragma unroll 2
    for (int i = 0; i < NT - 1; ++i) {
        const int ks = KS0 + i;
        const int cur = i & 1;
        {   // stage tile ks+1 into the other buffer (waits only this wave's own loads)
            half4v w = makew(ks + 1);
            *reinterpret_cast<half4v*>(&Al[cur ^ 1][srow * LDA + skk]) = w;
            if (ks + 2 < KSE) issue(ks + 2);   // overlaps the MFMA below
        }
        GP_MFMA(ks, cur);
        __syncthreads();   // single barrier/iter: all reads of Al[cur] and writes of
                           // Al[cur^1] complete before the buffers swap roles
    }
    GP_MFMA(KSE - 1, (NT - 1) & 1);   // last tile (already staged, no prefetch)

#undef GP_MFMA

    // epilogue: in-place overwrite is safe (rev is in-block; all Ha[rev] loads were
    // consumed into LDS before the final loop barrier)
    #pragma unroll
    for (int rt = 0; rt < 4; ++rt)
    #pragma unroll
    for (int ct = 0; ct < 4; ++ct)
    #pragma unroll
    for (int r = 0; r < 4; ++r) {
        const int row = rowblk + rt * 16 + quad * 4 + r;
        const int col = colbase + ct * 16 + m16;
        Ha[row * D_H + col] = (f16)fmaxf(acc[rt][ct][r], 0.f);
    }
}

// ---- output GEMM: Hv[a] = relu([M_v(512); V(133)] @ WtO + b_o).
//      R2-STRUCTURE (proven fastest variant): LDS double-buffer (1 barrier/iter) +
//      2-deep NAMED prefetch slots, rolled #pragma unroll 2 (trip 20, even), peeled
//      last iter.  Mn[arow] here is SEQUENTIAL (no gather), so deeper pipelining
//      pays and register pressure stays off the cliff.
template<bool F16M>
__global__ __launch_bounds__(512) void gemm_out(
    const float* __restrict__ V, const void* __restrict__ Mn,
    const float* __restrict__ Msc, const float* __restrict__ bo,
    const f16* __restrict__ WtS, f16* __restrict__ Hv)
{
    __shared__ __align__(16) f16 Al[2][64 * LDA];
    __shared__ float bo_s[D_H];
    const int tid = threadIdx.x;
    const int rowblk = blockIdx.x << 6;
    bo_s[tid] = bo[tid];
    const int srow = tid >> 3;
    const int skk  = (tid & 7) << 2;
    const int arow = min(rowblk + srow, N_ATOMS - 1);
    const int lane = tid & 63;
    const int quad = lane >> 4;
    const int m16  = lane & 15;
    const int colbase = (tid >> 6) << 6;
    const int cb0 = (tid >> 6) << 2;
    const f16* WtL = WtS + lane * 8;

    f32x4 acc[4][4];
    #pragma unroll
    for (int a = 0; a < 4; ++a)
    #pragma unroll
    for (int b = 0; b < 4; ++b)
    #pragma unroll
    for (int r = 0; r < 4; ++r) acc[a][b][r] = 0.f;

    char4 pq0, pq1; float ps0, ps1;
    half4v pm0, pm1;
    float pv0[4], pv1[4];

#define GO_ISSUE(S, KSV) do {                                                        \
    const int ks_i_ = (KSV);                                                         \
    if (ks_i_ < KSE) {                                                               \
        const int k0_ = ks_i_ << 5;                                                  \
        if (k0_ < D_H) {                                                             \
            if (F16M) {                                                              \
                pm##S = *reinterpret_cast<const half4v*>(&((const f16*)Mn)[arow * D_H + k0_ + skk]); \
            } else {                                                                 \
                pq##S = *reinterpret_cast<const char4*>(&((const char*)Mn)[arow * D_H + k0_ + skk]); \
                ps##S = Msc[arow * 16 + (k0_ >> 5)];                                 \
            }                                                                        \
        } else {                                                                     \
            const int kb_ = k0_ + skk - D_H;                                         \
            pv##S[0] = (kb_ + 0 < D_V) ? V[arow * D_V + kb_ + 0] : 0.f;              \
            pv##S[1] = (kb_ + 1 < D_V) ? V[arow * D_V + kb_ + 1] : 0.f;              \
            pv##S[2] = (kb_ + 2 < D_V) ? V[arow * D_V + kb_ + 2] : 0.f;              \
            pv##S[3] = (kb_ + 3 < D_V) ? V[arow * D_V + kb_ + 3] : 0.f;              \
        }                                                                            \
    }                                                                                \
} while (0)

#define GO_MAKEW(S, KSV, W) do {                                                     \
    const int k0_ = (KSV) << 5;                                                      \
    if (k0_ < D_H) {                                                                 \
        if (F16M) { W = pm##S; }                                                     \
        else {                                                                       \
            W[0] = (f16)((float)pq##S.x * ps##S);                                    \
            W[1] = (f16)((float)pq##S.y * ps##S);                                    \
            W[2] = (f16)((float)pq##S.z * ps##S);                                    \
            W[3] = (f16)((float)pq##S.w * ps##S);                                    \
        }                                                                            \
    } else {                                                                         \
        W[0] = (f16)pv##S[0]; W[1] = (f16)pv##S[1];                                  \
        W[2] = (f16)pv##S[2]; W[3] = (f16)pv##S[3];                                  \
    }                                                                                \
} while (0)

#define GO_MFMA(KSV, CUR) do {                                                       \
    half8 af[4];                                                                     \
    _Pragma("unroll")                                                                \
    for (int rt = 0; rt < 4; ++rt)                                                   \
        af[rt] = *reinterpret_cast<const half8*>(&Al[CUR][(rt * 16 + m16) * LDA + quad * 8]); \
    _Pragma("unroll")                                                                \
    for (int ct = 0; ct < 4; ++ct) {                                                 \
        const half8 bf = *reinterpret_cast<const half8*>(&WtL[(((cb0 + ct) * KSE + (KSV)) << 9)]); \
        _Pragma("unroll")                                                            \
        for (int rt = 0; rt < 4; ++rt)                                               \
            acc[rt][ct] = __builtin_amdgcn_mfma_f32_16x16x32_f16(af[rt], bf, acc[rt][ct], 0, 0, 0); \
    }                                                                                \
} while (0)

    GO_ISSUE(0, 0);
    GO_ISSUE(1, 1);
    {
        half4v w;
        GO_MAKEW(0, 0, w);
        *reinterpret_cast<half4v*>(&Al[0][srow * LDA + skk]) = w;
        GO_ISSUE(0, 2);
    }
    __syncthreads();

    #pragma unroll 2
    for (int i = 0; i < KSE - 1; ++i) {
        const int ks = i;
        const int cur = i & 1;
        {
            half4v w;
            if ((i + 1) & 1) { GO_MAKEW(1, ks + 1, w); }
            else             { GO_MAKEW(0, ks + 1, w); }
            *reinterpret_cast<half4v*>(&Al[cur ^ 1][srow * LDA + skk]) = w;
            if ((i + 1) & 1) { GO_ISSUE(1, ks + 3); }
            else             { GO_ISSUE(0, ks + 3); }
        }
        GO_MFMA(ks, cur);
        __syncthreads();
    }
    GO_MFMA(KSE - 1, (KSE - 1) & 1);

#undef GO_ISSUE
#undef GO_MAKEW
#undef GO_MFMA

    #pragma unroll
    for (int rt = 0; rt < 4; ++rt)
    #pragma unroll
    for (int ct = 0; ct < 4; ++ct)
    #pragma unroll
    for (int r = 0; r < 4; ++r) {
        const int row = rowblk + rt * 16 + quad * 4 + r;
        if (row < N_ATOMS) {
            const int col = colbase + ct * 16 + m16;
            Hv[row * D_H + col] = (f16)fmaxf(acc[rt][ct][r] + bo_s[col], 0.f);
        }
    }
}

// ---- molecule mean: batch sorted -> contiguous atom range per mol (binary search)
__global__ __launch_bounds__(512) void mol_mean(
    const f16* __restrict__ Hv, const int* __restrict__ batch, float* __restrict__ mean)
{
    const int m = blockIdx.x;
    __shared__ int sh[2];
    if (threadIdx.x == 0) {
        int lo = 0, hi = N_ATOMS;
        while (lo < hi) { int mid = (lo + hi) >> 1; if (batch[mid] < m) lo = mid + 1; else hi = mid; }
        sh[0] = lo;
        int lo2 = lo; hi = N_ATOMS;
        while (lo2 < hi) { int mid = (lo2 + hi) >> 1; if (batch[mid] < m + 1) lo2 = mid + 1; else hi = mid; }
        sh[1] = lo2;
    }
    __syncthreads();
    const int a0 = sh[0], a1 = sh[1];
    float acc = 0.f;
    for (int a = a0; a < a1; ++a) acc += (float)Hv[(size_t)a * D_H + threadIdx.x];
    mean[m * D_H + threadIdx.x] = acc / (float)max(a1 - a0, 1);
}

__global__ __launch_bounds__(256) void bn_stats(
    const float* __restrict__ mean_in, const float* __restrict__ gamma,
    const float* __restrict__ beta, float* __restrict__ An, float* __restrict__ Bn)
{
    const int n = blockIdx.x;
    const int tid = threadIdx.x;
    float s = 0.f, s2 = 0.f;
    for (int m = tid; m < N_MOLS; m += 256) {
        float h = mean_in[m * D_H + n];
        s += h; s2 += h * h;
    }
    for (int off = 32; off > 0; off >>= 1) {
        s  += __shfl_down(s, off);
        s2 += __shfl_down(s2, off);
    }
    __shared__ float sh[8];
    const int wave = tid >> 6, lane = tid & 63;
    if (lane == 0) { sh[wave] = s; sh[4 + wave] = s2; }
    __syncthreads();
    if (tid == 0) {
        float S  = sh[0] + sh[1] + sh[2] + sh[3];
        float S2 = sh[4] + sh[5] + sh[6] + sh[7];
        float mu = S / (float)N_MOLS;
        float var = fmaxf(S2 / (float)N_MOLS - mu * mu, 0.f);
        float sc = rsqrtf(var + 1e-5f) * gamma[n];
        An[n] = sc;
        Bn[n] = beta[n] - mu * sc;
    }
}

__global__ void bn_apply(const float* __restrict__ mean_in,
                         const float* __restrict__ An, const float* __restrict__ Bn,
                         float* __restrict__ out)
{
    int gid = blockIdx.x * blockDim.x + threadIdx.x;
    int n = gid & 511;
    out[gid] = mean_in[gid] * An[n] + Bn[n];
}

extern "C" void kernel_launch(void* const* d_in, const int* in_sizes, int n_in,
                              void* d_out, int out_size, void* d_ws, size_t ws_size,
                              hipStream_t stream)
{
    (void)in_sizes; (void)n_in; (void)out_size;
    const float* V     = (const float*)d_in[0];
    const float* E     = (const float*)d_in[1];
    const int*   esrc  = (const int*)d_in[2];
    const int*   edst  = (const int*)d_in[3];
    const int*   batch = (const int*)d_in[4];
    const float* Wi    = (const float*)d_in[5];
    const float* Wh    = (const float*)d_in[6];
    const float* Wo    = (const float*)d_in[7];
    const float* bo    = (const float*)d_in[8];
    const float* gam   = (const float*)d_in[9];
    const float* bet   = (const float*)d_in[10];
    float* out = (float*)d_out;

    // workspace layout
    //  int8 mode total: 265,396,864 B.  f16 mode total: 310,196,864 B (needs ws_size >= that).
    char* ws = (char*)d_ws;
    f16*   WtC  = (f16*)(ws + 0);                   //    688,128 B (swizzled)
    f16*   WtO  = (f16*)(ws + 688128);              //    688,128 B (swizzled)
    int*   off  = (int*)(ws + 1376256);             //    400,128 B (N_ATOMS+1 ints)
    int*   eid  = (int*)(ws + 1776384);             //    800,000 B
    int*   cnt  = (int*)(ws + 2576384);             //    400,000 B (also 'pos' cursor)
    float* An   = (float*)(ws + 2992768);           //      2,048 B
    float* Bn   = (float*)(ws + 2994816);           //      2,048 B
    f16*   Ha   = (f16*)(ws + 2996864);             // 204,800,000 B (edge states; reused as Hv)
    void*  Mn   = (void*)(ws + 207796864);          // int8: 51.2 MB | f16: 102.4 MB
    float* Msc  = (float*)(ws + 258996864);         //   6,400,000 B scales (int8 mode only)
    f16*   Hv   = Ha;                                // Ha is dead after final seg_csr
    float* mean = out;                               // mol means live in d_out

    const bool f16m = ws_size >= 310196864ULL;

    // weights (swizzled to MFMA fragment order)
    wt_build_swz<<<(D_H * KC + 255) / 256, 256, 0, stream>>>(Wh, D_H, Wi, D_V + D_E, WtC);
    wt_build_swz<<<(D_H * KC + 255) / 256, 256, 0, stream>>>(Wo + D_V * D_H, D_H, Wo, D_V, WtO);

    // CSR over edge_dst (cnt doubles as scatter cursor 'pos')
    hipMemsetAsync(cnt, 0, 400000, stream);
    csr_hist<<<(N_EDGES + 511) / 512, 512, 0, stream>>>(edst, cnt);
    csr_scan<<<1, 1024, 0, stream>>>(cnt, off, cnt);
    csr_scatter<<<(N_EDGES + 511) / 512, 512, 0, stream>>>(edst, cnt, eid);

    if (f16m) {
        gemm_pass<true, 16><<<N_EDGES / 64, 512, 0, stream>>>(V, E, esrc, Mn, Msc, Ha, WtC);
        for (int it = 0; it < 2; ++it) {
            seg_csr<true><<<N_ATOMS / 8, 512, 0, stream>>>(Ha, off, eid, Mn, Msc);
            gemm_pass<true, 0><<<N_EDGES / 64, 512, 0, stream>>>(V, E, esrc, Mn, Msc, Ha, WtC);
        }
        seg_csr<true><<<N_ATOMS / 8, 512, 0, stream>>>(Ha, off, eid, Mn, Msc);
        gemm_out<true><<<(N_ATOMS + 63) / 64, 512, 0, stream>>>(V, Mn, Msc, bo, WtO, Hv);
    } else {
        gemm_pass<false, 16><<<N_EDGES / 64, 512, 0, stream>>>(V, E, esrc, Mn, Msc, Ha, WtC);
        for (int it = 0; it < 2; ++it) {
            seg_csr<false><<<N_ATOMS / 8, 512, 0, stream>>>(Ha, off, eid, Mn, Msc);
            gemm_pass<false, 0><<<N_EDGES / 64, 512, 0, stream>>>(V, E, esrc, Mn, Msc, Ha, WtC);
        }
        seg_csr<false><<<N_ATOMS / 8, 512, 0, stream>>>(Ha, off, eid, Mn, Msc);
        gemm_out<false><<<(N_ATOMS + 63) / 64, 512, 0, stream>>>(V, Mn, Msc, bo, WtO, Hv);
    }

    mol_mean<<<N_MOLS, 512, 0, stream>>>(Hv, batch, mean);
    bn_stats<<<D_H, 256, 0, stream>>>(mean, gam, bet, An, Bn);
    bn_apply<<<(N_MOLS * D_H) / 256, 256, 0, stream>>>(mean, An, Bn, out);
}

// Round 12
// 1252.788 us; speedup vs baseline: 1.0493x; 1.0089x over previous
//
#include <hip/hip_runtime.h>

typedef _Float16 f16;
typedef _Float16 half8 __attribute__((ext_vector_type(8)));
typedef _Float16 half4v __attribute__((ext_vector_type(4)));
typedef float f32x4 __attribute__((ext_vector_type(4)));

#define N_ATOMS 100000
#define N_EDGES 200000
#define N_MOLS  4096
#define D_V 133
#define D_E 14
#define D_H 512
#define KC  672        // padded K for [W_h(512); W_i(147)] and [W_o_m(512); W_o_v(133)]
#define KSE 21         // 32-wide K tiles
#define LDA 40         // LDS A-tile row stride (f16 elems): 80 B rows

// ---- weight build, swizzled to MFMA fragment order:
//   B_swz[(((n>>4)*21 + (k>>5))*64 + ((k>>3)&3)*16 + (n&15))*8 + (k&7)] = W[k][n]
__global__ void wt_build_swz(const float* __restrict__ W1, int r1,
                             const float* __restrict__ W2, int r2,
                             f16* __restrict__ WtS) {
    int gid = blockIdx.x * blockDim.x + threadIdx.x;
    if (gid >= D_H * KC) return;
    int n = gid / KC;
    int k = gid - n * KC;
    float x = 0.f;
    if (k < r1) x = W1[k * D_H + n];
    else if (k < r1 + r2) x = W2[(k - r1) * D_H + n];
    const int dst = ((((n >> 4) * KSE + (k >> 5)) << 6) + (((k >> 3) & 3) << 4) + (n & 15)) * 8 + (k & 7);
    WtS[dst] = (f16)x;
}

// ---- CSR build over edge_dst
__global__ void csr_hist(const int* __restrict__ edst, int* __restrict__ cnt) {
    int e = blockIdx.x * blockDim.x + threadIdx.x;
    if (e < N_EDGES) atomicAdd(&cnt[edst[e]], 1);
}

__global__ __launch_bounds__(1024) void csr_scan(const int* __restrict__ cnt,
                                                 int* __restrict__ off, int* __restrict__ pos) {
    __shared__ int sums[1024];
    const int tid = threadIdx.x;
    const int lo = tid * 100;            // 1000 active threads x 100 atoms, int4-aligned
    int s = 0;
    if (lo < N_ATOMS) {
        const int4* c4 = reinterpret_cast<const int4*>(cnt + lo);
        #pragma unroll
        for (int i = 0; i < 25; ++i) { int4 v = c4[i]; s += v.x + v.y + v.z + v.w; }
    }
    sums[tid] = s;
    __syncthreads();
    for (int d = 1; d < 1024; d <<= 1) {
        int v = (tid >= d) ? sums[tid - d] : 0;
        __syncthreads();
        sums[tid] += v;
        __syncthreads();
    }
    int run = sums[tid] - s;  // exclusive base
    if (lo < N_ATOMS) {
        const int4* c4 = reinterpret_cast<const int4*>(cnt + lo);
        for (int i = 0; i < 25; ++i) {
            int4 v = c4[i];          // load before aliased pos-store (pos == cnt)
            const int b = lo + i * 4;
            off[b]     = run; pos[b]     = run; run += v.x;
            off[b + 1] = run; pos[b + 1] = run; run += v.y;
            off[b + 2] = run; pos[b + 2] = run; run += v.z;
            off[b + 3] = run; pos[b + 3] = run; run += v.w;
        }
    }
    if (tid == 1023) off[N_ATOMS] = run;   // s==0 here -> run == total
}

__global__ void csr_scatter(const int* __restrict__ edst, int* __restrict__ pos,
                            int* __restrict__ eid) {
    int e = blockIdx.x * blockDim.x + threadIdx.x;
    if (e < N_EDGES) {
        int idx = atomicAdd(&pos[edst[e]], 1);
        eid[idx] = e;
    }
}

// ---- node message sum via CSR gather.  F16M: store f16 rows.  else: block-scaled int8.
template<bool F16M>
__global__ __launch_bounds__(512) void seg_csr(
    const f16* __restrict__ H, const int* __restrict__ off, const int* __restrict__ eid,
    void* __restrict__ MnOut, float* __restrict__ Msc)
{
    const int n = blockIdx.x * 8 + (threadIdx.x >> 6);
    const int lane = threadIdx.x & 63;
    const int j0 = off[n], j1 = off[n + 1];
    float acc[8];
    #pragma unroll
    for (int k = 0; k < 8; ++k) acc[k] = 0.f;
    int e_cur = (j0 < j1) ? eid[j0] : 0;
    for (int j = j0; j < j1; ++j) {
        const int e_nxt = (j + 1 < j1) ? eid[j + 1] : 0;   // prefetch next index
        const half8 h = *reinterpret_cast<const half8*>(&H[e_cur * D_H + lane * 8]);
        #pragma unroll
        for (int k = 0; k < 8; ++k) acc[k] += (float)h[k];
        e_cur = e_nxt;
    }
    if (F16M) {
        half8 o;
        #pragma unroll
        for (int k = 0; k < 8; ++k) o[k] = (f16)acc[k];
        *reinterpret_cast<half8*>(&((f16*)MnOut)[n * D_H + lane * 8]) = o;
    } else {
        float m = 0.f;
        #pragma unroll
        for (int k = 0; k < 8; ++k) m = fmaxf(m, fabsf(acc[k]));
        m = fmaxf(m, __shfl_xor(m, 1));
        m = fmaxf(m, __shfl_xor(m, 2));
        m = fmaxf(m, 1e-20f);
        const float s = m * (1.f / 127.f);
        const float inv_s = 127.f / m;
        if ((lane & 3) == 0) Msc[n * 16 + (lane >> 2)] = s;
        int q[8];
        #pragma unroll
        for (int k = 0; k < 8; ++k) q[k] = __float2int_rn(acc[k] * inv_s);
        uint2 o;
        o.x = (q[0] & 0xff) | ((q[1] & 0xff) << 8) | ((q[2] & 0xff) << 16) | ((unsigned)(q[3] & 0xff) << 24);
        o.y = (q[4] & 0xff) | ((q[5] & 0xff) << 8) | ((q[6] & 0xff) << 16) | ((unsigned)(q[7] & 0xff) << 24);
        *reinterpret_cast<uint2*>(&((unsigned int*)MnOut)[n * 128 + lane * 2]) = o;
    }
}

// ---- fused message-passing GEMM (in-place on Ha), BK=32, 1-deep prefetch, swizzled B.
//      MEASURED OPTIMUM — hold.  Full structure matrix (R0-R10):
//        R1 full-unroll 3-deep: spill (WRITE 201->480MB), -27%.
//        R2 dbuf 2-deep slots: VGPR 72 -> 1 blk/CU cliff, -44%.
//        R3/R7 smaller BM (higher occupancy): B-reuse drop + barrier count, -50%.
//        R6 dbuf raw-barrier+fences: compiler overlap lost, -15%.
//        R8 setprio(T5): null.
//        R9 gather split to streaming pre-pass: +32us/pass net.
//        R10 dbuf single-__syncthreads: gather-wait lands between MFMA and barrier
//             (convoy), -5%.  The 2-barrier ordering keeps the vmcnt wait BEFORE
//             the publish barrier, overlapped with other waves' MFMA.
//      64 arch + 64 AGPR = 128 regs = 4 waves/SIMD -> 2 blocks/CU; TLP hides the
//      Mn[sv] gather.  Sync audit (R11): all Ha[rev] reads vmcnt-consumed >= 5
//      barrier-pairs before epilogue stores; rev in-block; LDS reads lgkmcnt-waited
//      before MFMA.  Do not change without re-running the matrix.
template<bool F16M>
__global__ __launch_bounds__(512) void gemm_pass(
    const float* __restrict__ V, const float* __restrict__ E,
    const int* __restrict__ esrc, const void* __restrict__ Mn,
    const float* __restrict__ Msc,
    f16* __restrict__ Ha, const f16* __restrict__ WtS, int ks_begin)
{
    __shared__ __align__(16) f16 Al[64 * LDA];
    const int tid = threadIdx.x;
    const int rowblk = blockIdx.x << 6;
    const int srow = tid >> 3;
    const int skk  = (tid & 7) << 2;
    const int e_s  = rowblk + srow;
    const int sv   = esrc[e_s];
    const int rev  = e_s ^ 1;
    const int lane = tid & 63;
    const int quad = lane >> 4;
    const int m16  = lane & 15;
    const int colbase = (tid >> 6) << 6;
    const int cb0 = (tid >> 6) << 2;          // first of this wave's 4 col-tiles
    const f16* WtL = WtS + lane * 8;          // lane-constant fragment base

    f32x4 acc[4][4];
    #pragma unroll
    for (int a = 0; a < 4; ++a)
    #pragma unroll
    for (int b = 0; b < 4; ++b)
    #pragma unroll
    for (int r = 0; r < 4; ++r) acc[a][b][r] = 0.f;

    // prefetch registers
    char4 pq; float ps; half4v pm; half4v ph; float pv[4];
    auto issue = [&](int ks) {
        const int k0 = ks << 5;
        if (k0 < D_H) {
            if (F16M) {
                pm = *reinterpret_cast<const half4v*>(&((const f16*)Mn)[sv * D_H + k0 + skk]);
            } else {
                pq = *reinterpret_cast<const char4*>(&((const char*)Mn)[sv * D_H + k0 + skk]);
                ps = Msc[sv * 16 + (k0 >> 5)];
            }
            ph = *reinterpret_cast<const half4v*>(&Ha[rev * D_H + k0 + skk]);
        } else {
            #pragma unroll
            for (int j = 0; j < 4; ++j) {
                const int kk = k0 + skk + j - D_H;
                float x = 0.f;
                if (kk < D_V) x = V[sv * D_V + kk];
                else if (kk < D_V + D_E) x = E[e_s * D_E + (kk - D_V)];
                pv[j] = x;
            }
        }
    };

    issue(ks_begin);
    for (int ks = ks_begin; ks < KSE; ++ks) {
        const int k0 = ks << 5;
        half4v w;
        if (k0 < D_H) {
            if (F16M) {
                w = pm - ph;   // packed f16 subtract
            } else {
                w[0] = (f16)((float)pq.x * ps - (float)ph[0]);
                w[1] = (f16)((float)pq.y * ps - (float)ph[1]);
                w[2] = (f16)((float)pq.z * ps - (float)ph[2]);
                w[3] = (f16)((float)pq.w * ps - (float)ph[3]);
            }
        } else {
            w[0] = (f16)pv[0]; w[1] = (f16)pv[1]; w[2] = (f16)pv[2]; w[3] = (f16)pv[3];
        }
        __syncthreads();
        *reinterpret_cast<half4v*>(&Al[srow * LDA + skk]) = w;
        __syncthreads();
        if (ks + 1 < KSE) issue(ks + 1);  // overlap with MFMA below
        half8 af[4];
        #pragma unroll
        for (int rt = 0; rt < 4; ++rt)
            af[rt] = *reinterpret_cast<const half8*>(&Al[(rt * 16 + m16) * LDA + quad * 8]);
        #pragma unroll
        for (int ct = 0; ct < 4; ++ct) {
            const half8 bf = *reinterpret_cast<const half8*>(&WtL[(((cb0 + ct) * KSE + ks) << 9)]);
            #pragma unroll
            for (int rt = 0; rt < 4; ++rt)
                acc[rt][ct] = __builtin_amdgcn_mfma_f32_16x16x32_f16(af[rt], bf, acc[rt][ct], 0, 0, 0);
        }
    }

    // epilogue: in-place overwrite is safe (all Ha[rev] reads are in-block, barrier-ordered)
    #pragma unroll
    for (int rt = 0; rt < 4; ++rt)
    #pragma unroll
    for (int ct = 0; ct < 4; ++ct)
    #pragma unroll
    for (int r = 0; r < 4; ++r) {
        const int row = rowblk + rt * 16 + quad * 4 + r;
        const int col = colbase + ct * 16 + m16;
        Ha[row * D_H + col] = (f16)fmaxf(acc[rt][ct][r], 0.f);
    }
}

// ---- output GEMM: Hv[a] = relu([M_v(512); V(133)] @ WtO + b_o).
//      R2-STRUCTURE (proven fastest variant): LDS double-buffer (1 barrier/iter) +
//      2-deep NAMED prefetch slots, rolled #pragma unroll 2 (trip 20, even), peeled
//      last iter.  Unlike gemm_pass, Mn[arow] here is SEQUENTIAL (no gather), so
//      deeper pipelining pays and register pressure stays off the cliff.
template<bool F16M>
__global__ __launch_bounds__(512) void gemm_out(
    const float* __restrict__ V, const void* __restrict__ Mn,
    const float* __restrict__ Msc, const float* __restrict__ bo,
    const f16* __restrict__ WtS, f16* __restrict__ Hv)
{
    __shared__ __align__(16) f16 Al[2][64 * LDA];
    __shared__ float bo_s[D_H];
    const int tid = threadIdx.x;
    const int rowblk = blockIdx.x << 6;
    bo_s[tid] = bo[tid];
    const int srow = tid >> 3;
    const int skk  = (tid & 7) << 2;
    const int arow = min(rowblk + srow, N_ATOMS - 1);
    const int lane = tid & 63;
    const int quad = lane >> 4;
    const int m16  = lane & 15;
    const int colbase = (tid >> 6) << 6;
    const int cb0 = (tid >> 6) << 2;
    const f16* WtL = WtS + lane * 8;

    f32x4 acc[4][4];
    #pragma unroll
    for (int a = 0; a < 4; ++a)
    #pragma unroll
    for (int b = 0; b < 4; ++b)
    #pragma unroll
    for (int r = 0; r < 4; ++r) acc[a][b][r] = 0.f;

    char4 pq0, pq1; float ps0, ps1;
    half4v pm0, pm1;
    float pv0[4], pv1[4];

#define GO_ISSUE(S, KSV) do {                                                        \
    const int ks_i_ = (KSV);                                                         \
    if (ks_i_ < KSE) {                                                               \
        const int k0_ = ks_i_ << 5;                                                  \
        if (k0_ < D_H) {                                                             \
            if (F16M) {                                                              \
                pm##S = *reinterpret_cast<const half4v*>(&((const f16*)Mn)[arow * D_H + k0_ + skk]); \
            } else {                                                                 \
                pq##S = *reinterpret_cast<const char4*>(&((const char*)Mn)[arow * D_H + k0_ + skk]); \
                ps##S = Msc[arow * 16 + (k0_ >> 5)];                                 \
            }                                                                        \
        } else {                                                                     \
            const int kb_ = k0_ + skk - D_H;                                         \
            pv##S[0] = (kb_ + 0 < D_V) ? V[arow * D_V + kb_ + 0] : 0.f;              \
            pv##S[1] = (kb_ + 1 < D_V) ? V[arow * D_V + kb_ + 1] : 0.f;              \
            pv##S[2] = (kb_ + 2 < D_V) ? V[arow * D_V + kb_ + 2] : 0.f;              \
            pv##S[3] = (kb_ + 3 < D_V) ? V[arow * D_V + kb_ + 3] : 0.f;              \
        }                                                                            \
    }                                                                                \
} while (0)

#define GO_MAKEW(S, KSV, W) do {                                                     \
    const int k0_ = (KSV) << 5;                                                      \
    if (k0_ < D_H) {                                                                 \
        if (F16M) { W = pm##S; }                                                     \
        else {                                                                       \
            W[0] = (f16)((float)pq##S.x * ps##S);                                    \
            W[1] = (f16)((float)pq##S.y * ps##S);                                    \
            W[2] = (f16)((float)pq##S.z * ps##S);                                    \
            W[3] = (f16)((float)pq##S.w * ps##S);                                    \
        }                                                                            \
    } else {                                                                         \
        W[0] = (f16)pv##S[0]; W[1] = (f16)pv##S[1];                                  \
        W[2] = (f16)pv##S[2]; W[3] = (f16)pv##S[3];                                  \
    }                                                                                \
} while (0)

#define GO_MFMA(KSV, CUR) do {                                                       \
    half8 af[4];                                                                     \
    _Pragma("unroll")                                                                \
    for (int rt = 0; rt < 4; ++rt)                                                   \
        af[rt] = *reinterpret_cast<const half8*>(&Al[CUR][(rt * 16 + m16) * LDA + quad * 8]); \
    _Pragma("unroll")                                                                \
    for (int ct = 0; ct < 4; ++ct) {                                                 \
        const half8 bf = *reinterpret_cast<const half8*>(&WtL[(((cb0 + ct) * KSE + (KSV)) << 9)]); \
        _Pragma("unroll")                                                            \
        for (int rt = 0; rt < 4; ++rt)                                               \
            acc[rt][ct] = __builtin_amdgcn_mfma_f32_16x16x32_f16(af[rt], bf, acc[rt][ct], 0, 0, 0); \
    }                                                                                \
} while (0)

    GO_ISSUE(0, 0);
    GO_ISSUE(1, 1);
    {
        half4v w;
        GO_MAKEW(0, 0, w);
        *reinterpret_cast<half4v*>(&Al[0][srow * LDA + skk]) = w;
        GO_ISSUE(0, 2);
    }
    __syncthreads();

    #pragma unroll 2
    for (int i = 0; i < KSE - 1; ++i) {
        const int ks = i;
        const int cur = i & 1;
        {
            half4v w;
            if ((i + 1) & 1) { GO_MAKEW(1, ks + 1, w); }
            else             { GO_MAKEW(0, ks + 1, w); }
            *reinterpret_cast<half4v*>(&Al[cur ^ 1][srow * LDA + skk]) = w;
            if ((i + 1) & 1) { GO_ISSUE(1, ks + 3); }
            else             { GO_ISSUE(0, ks + 3); }
        }
        GO_MFMA(ks, cur);
        __syncthreads();
    }
    GO_MFMA(KSE - 1, (KSE - 1) & 1);

#undef GO_ISSUE
#undef GO_MAKEW
#undef GO_MFMA

    #pragma unroll
    for (int rt = 0; rt < 4; ++rt)
    #pragma unroll
    for (int ct = 0; ct < 4; ++ct)
    #pragma unroll
    for (int r = 0; r < 4; ++r) {
        const int row = rowblk + rt * 16 + quad * 4 + r;
        if (row < N_ATOMS) {
            const int col = colbase + ct * 16 + m16;
            Hv[row * D_H + col] = (f16)fmaxf(acc[rt][ct][r] + bo_s[col], 0.f);
        }
    }
}

// ---- molecule mean: batch sorted -> contiguous atom range per mol (binary search)
__global__ __launch_bounds__(512) void mol_mean(
    const f16* __restrict__ Hv, const int* __restrict__ batch, float* __restrict__ mean)
{
    const int m = blockIdx.x;
    __shared__ int sh[2];
    if (threadIdx.x == 0) {
        int lo = 0, hi = N_ATOMS;
        while (lo < hi) { int mid = (lo + hi) >> 1; if (batch[mid] < m) lo = mid + 1; else hi = mid; }
        sh[0] = lo;
        int lo2 = lo; hi = N_ATOMS;
        while (lo2 < hi) { int mid = (lo2 + hi) >> 1; if (batch[mid] < m + 1) lo2 = mid + 1; else hi = mid; }
        sh[1] = lo2;
    }
    __syncthreads();
    const int a0 = sh[0], a1 = sh[1];
    float acc = 0.f;
    for (int a = a0; a < a1; ++a) acc += (float)Hv[(size_t)a * D_H + threadIdx.x];
    mean[m * D_H + threadIdx.x] = acc / (float)max(a1 - a0, 1);
}

__global__ __launch_bounds__(256) void bn_stats(
    const float* __restrict__ mean_in, const float* __restrict__ gamma,
    const float* __restrict__ beta, float* __restrict__ An, float* __restrict__ Bn)
{
    const int n = blockIdx.x;
    const int tid = threadIdx.x;
    float s = 0.f, s2 = 0.f;
    for (int m = tid; m < N_MOLS; m += 256) {
        float h = mean_in[m * D_H + n];
        s += h; s2 += h * h;
    }
    for (int off = 32; off > 0; off >>= 1) {
        s  += __shfl_down(s, off);
        s2 += __shfl_down(s2, off);
    }
    __shared__ float sh[8];
    const int wave = tid >> 6, lane = tid & 63;
    if (lane == 0) { sh[wave] = s; sh[4 + wave] = s2; }
    __syncthreads();
    if (tid == 0) {
        float S  = sh[0] + sh[1] + sh[2] + sh[3];
        float S2 = sh[4] + sh[5] + sh[6] + sh[7];
        float mu = S / (float)N_MOLS;
        float var = fmaxf(S2 / (float)N_MOLS - mu * mu, 0.f);
        float sc = rsqrtf(var + 1e-5f) * gamma[n];
        An[n] = sc;
        Bn[n] = beta[n] - mu * sc;
    }
}

__global__ void bn_apply(const float* __restrict__ mean_in,
                         const float* __restrict__ An, const float* __restrict__ Bn,
                         float* __restrict__ out)
{
    int gid = blockIdx.x * blockDim.x + threadIdx.x;
    int n = gid & 511;
    out[gid] = mean_in[gid] * An[n] + Bn[n];
}

extern "C" void kernel_launch(void* const* d_in, const int* in_sizes, int n_in,
                              void* d_out, int out_size, void* d_ws, size_t ws_size,
                              hipStream_t stream)
{
    (void)in_sizes; (void)n_in; (void)out_size;
    const float* V     = (const float*)d_in[0];
    const float* E     = (const float*)d_in[1];
    const int*   esrc  = (const int*)d_in[2];
    const int*   edst  = (const int*)d_in[3];
    const int*   batch = (const int*)d_in[4];
    const float* Wi    = (const float*)d_in[5];
    const float* Wh    = (const float*)d_in[6];
    const float* Wo    = (const float*)d_in[7];
    const float* bo    = (const float*)d_in[8];
    const float* gam   = (const float*)d_in[9];
    const float* bet   = (const float*)d_in[10];
    float* out = (float*)d_out;

    // workspace layout
    //  int8 mode total: 265,396,864 B.  f16 mode total: 310,196,864 B (needs ws_size >= that).
    char* ws = (char*)d_ws;
    f16*   WtC  = (f16*)(ws + 0);                   //    688,128 B (swizzled)
    f16*   WtO  = (f16*)(ws + 688128);              //    688,128 B (swizzled)
    int*   off  = (int*)(ws + 1376256);             //    400,128 B (N_ATOMS+1 ints)
    int*   eid  = (int*)(ws + 1776384);             //    800,000 B
    int*   cnt  = (int*)(ws + 2576384);             //    400,000 B (also 'pos' cursor)
    float* An   = (float*)(ws + 2992768);           //      2,048 B
    float* Bn   = (float*)(ws + 2994816);           //      2,048 B
    f16*   Ha   = (f16*)(ws + 2996864);             // 204,800,000 B (edge states; reused as Hv)
    void*  Mn   = (void*)(ws + 207796864);          // int8: 51.2 MB | f16: 102.4 MB
    float* Msc  = (float*)(ws + 258996864);         //   6,400,000 B scales (int8 mode only)
    f16*   Hv   = Ha;                                // Ha is dead after final seg_csr
    float* mean = out;                               // mol means live in d_out

    const bool f16m = ws_size >= 310196864ULL;

    // weights (swizzled to MFMA fragment order)
    wt_build_swz<<<(D_H * KC + 255) / 256, 256, 0, stream>>>(Wh, D_H, Wi, D_V + D_E, WtC);
    wt_build_swz<<<(D_H * KC + 255) / 256, 256, 0, stream>>>(Wo + D_V * D_H, D_H, Wo, D_V, WtO);

    // CSR over edge_dst (cnt doubles as scatter cursor 'pos')
    hipMemsetAsync(cnt, 0, 400000, stream);
    csr_hist<<<(N_EDGES + 511) / 512, 512, 0, stream>>>(edst, cnt);
    csr_scan<<<1, 1024, 0, stream>>>(cnt, off, cnt);
    csr_scatter<<<(N_EDGES + 511) / 512, 512, 0, stream>>>(edst, cnt, eid);

    if (f16m) {
        gemm_pass<true><<<N_EDGES / 64, 512, 0, stream>>>(V, E, esrc, Mn, Msc, Ha, WtC, 16);
        for (int it = 0; it < 2; ++it) {
            seg_csr<true><<<N_ATOMS / 8, 512, 0, stream>>>(Ha, off, eid, Mn, Msc);
            gemm_pass<true><<<N_EDGES / 64, 512, 0, stream>>>(V, E, esrc, Mn, Msc, Ha, WtC, 0);
        }
        seg_csr<true><<<N_ATOMS / 8, 512, 0, stream>>>(Ha, off, eid, Mn, Msc);
        gemm_out<true><<<(N_ATOMS + 63) / 64, 512, 0, stream>>>(V, Mn, Msc, bo, WtO, Hv);
    } else {
        gemm_pass<false><<<N_EDGES / 64, 512, 0, stream>>>(V, E, esrc, Mn, Msc, Ha, WtC, 16);
        for (int it = 0; it < 2; ++it) {
            seg_csr<false><<<N_ATOMS / 8, 512, 0, stream>>>(Ha, off, eid, Mn, Msc);
            gemm_pass<false><<<N_EDGES / 64, 512, 0, stream>>>(V, E, esrc, Mn, Msc, Ha, WtC, 0);
        }
        seg_csr<false><<<N_ATOMS / 8, 512, 0, stream>>>(Ha, off, eid, Mn, Msc);
        gemm_out<false><<<(N_ATOMS + 63) / 64, 512, 0, stream>>>(V, Mn, Msc, bo, WtO, Hv);
    }

    mol_mean<<<N_MOLS, 512, 0, stream>>>(Hv, batch, mean);
    bn_stats<<<D_H, 256, 0, stream>>>(mean, gam, bet, An, Bn);
    bn_apply<<<(N_MOLS * D_H) / 256, 256, 0, stream>>>(mean, An, Bn, out);
}